// Round 1
// baseline (279.304 us; speedup 1.0000x reference)
//
#include <hip/hip_runtime.h>
#include <math.h>

#define NN   6144
#define FIN  512
#define HIDN 64
#define NC   40
#define NH   3
#define CAP  128           // max neighbors kept (deg ~ 61 +/- 8, 128 is ~8.5 sigma)
#define NCHUNK (CAP / 64)
#define LALPHA 0.2f

// ---------------- CSR build: one wave per row, ballot compaction ----------------
__global__ __launch_bounds__(256) void k_csr(const float* __restrict__ adj,
                                             int* __restrict__ nbr,
                                             int* __restrict__ deg) {
    int row  = blockIdx.x * 4 + (threadIdx.x >> 6);
    int lane = threadIdx.x & 63;
    const float* arow = adj + (size_t)row * NN;
    int* nrow = nbr + (size_t)row * CAP;
    int cnt = 0;
    for (int base = 0; base < NN; base += 256) {
        float4 v = *reinterpret_cast<const float4*>(arow + base + lane * 4);
        float vv[4] = {v.x, v.y, v.z, v.w};
#pragma unroll
        for (int q = 0; q < 4; q++) {
            bool on = vv[q] > 0.0f;
            unsigned long long mask = __ballot(on);
            if (on) {
                int pos = cnt + __popcll(mask & ((1ull << lane) - 1ull));
                if (pos < CAP) nrow[pos] = base + lane * 4 + q;
            }
            cnt += __popcll(mask);
        }
    }
    if (lane == 0) deg[row] = cnt < CAP ? cnt : CAP;
}

// ---------------- Layer-1 GEMM: Wh1[h][n][o] = sum_f x[n][f] * W1[h][f][o] ----------------
// block: 256 thr = 4 waves; block covers 16 rows x 64 cols; each thread 4 rows
__global__ __launch_bounds__(256) void k_gemm1(const float* __restrict__ x,
                                               const float* __restrict__ W,
                                               float* __restrict__ Wh) {
    int h  = blockIdx.y;
    int n0 = blockIdx.x * 16;
    int o  = threadIdx.x & 63;
    int r  = threadIdx.x >> 6;          // 0..3
    const float* Wp = W + (size_t)h * FIN * HIDN + o;
    const float* x0 = x + (size_t)(n0 + r * 4) * FIN;
    float acc0 = 0.f, acc1 = 0.f, acc2 = 0.f, acc3 = 0.f;
#pragma unroll 4
    for (int f = 0; f < FIN; f++) {
        float w = Wp[(size_t)f * HIDN];
        acc0 += x0[f] * w;
        acc1 += x0[FIN + f] * w;
        acc2 += x0[2 * FIN + f] * w;
        acc3 += x0[3 * FIN + f] * w;
    }
    float* outp = Wh + ((size_t)h * NN + n0 + r * 4) * HIDN + o;
    outp[0 * HIDN] = acc0;
    outp[1 * HIDN] = acc1;
    outp[2 * HIDN] = acc2;
    outp[3 * HIDN] = acc3;
}

// ---------------- e_src/e_dst for layer 1: one wave per (h,n), lane = o ----------------
__global__ __launch_bounds__(256) void k_e1(const float* __restrict__ Wh,
                                            const float* __restrict__ a_src,
                                            const float* __restrict__ a_dst,
                                            float* __restrict__ es,
                                            float* __restrict__ ed) {
    int gw   = blockIdx.x * 4 + (threadIdx.x >> 6);
    int lane = threadIdx.x & 63;
    int h = gw / NN, n = gw % NN;
    float v = Wh[((size_t)h * NN + n) * HIDN + lane];
    float s = v * a_src[h * HIDN + lane];
    float d = v * a_dst[h * HIDN + lane];
#pragma unroll
    for (int off = 32; off; off >>= 1) {
        s += __shfl_xor(s, off);
        d += __shfl_xor(d, off);
    }
    if (lane == 0) { es[h * NN + n] = s; ed[h * NN + n] = d; }
}

// ---------------- Layer-1 attention + aggregate + head-mean + ReLU ----------------
// one wave (64 thr) per node; lane = output channel o
__global__ __launch_bounds__(64) void k_attn1(const int* __restrict__ nbr,
                                              const int* __restrict__ deg,
                                              const float* __restrict__ Wh,
                                              const float* __restrict__ es,
                                              const float* __restrict__ ed,
                                              float* __restrict__ x2) {
    int n = blockIdx.x;
    int lane = threadIdx.x;
    int d = deg[n];
    const int* nrow = nbr + (size_t)n * CAP;
    float acc = 0.f;
    for (int h = 0; h < NH; h++) {
        float esv = es[h * NN + n];
        float sv[NCHUNK]; int mv[NCHUNK];
        float mx = -INFINITY;
#pragma unroll
        for (int c = 0; c < NCHUNK; c++) {
            int k = c * 64 + lane;
            float s = -INFINITY; int mm = 0;
            if (k < d) {
                mm = nrow[k];
                float e = esv + ed[h * NN + mm];
                s = e > 0.f ? e : LALPHA * e;
            }
            sv[c] = s; mv[c] = mm;
            mx = fmaxf(mx, s);
        }
#pragma unroll
        for (int off = 32; off; off >>= 1) mx = fmaxf(mx, __shfl_xor(mx, off));
        float pv[NCHUNK]; float psum = 0.f;
#pragma unroll
        for (int c = 0; c < NCHUNK; c++) {
            int k = c * 64 + lane;
            float p = (k < d) ? __expf(sv[c] - mx) : 0.f;
            pv[c] = p; psum += p;
        }
#pragma unroll
        for (int off = 32; off; off >>= 1) psum += __shfl_xor(psum, off);
        float inv = 1.f / psum;
        float hacc = 0.f;
        for (int c = 0; c < NCHUNK; c++) {
            int kbase = c * 64;
            if (kbase >= d) break;
            int cnt = min(64, d - kbase);
            for (int j = 0; j < cnt; j++) {
                float p  = __shfl(pv[c], j);
                int   mm = __shfl(mv[c], j);
                hacc += p * Wh[((size_t)h * NN + mm) * HIDN + lane];
            }
        }
        acc += hacc * inv;
    }
    x2[(size_t)n * HIDN + lane] = fmaxf(acc * (1.f / NH), 0.f);
}

// ---------------- Layer-2 GEMM: Wh2[h][n][c] = sum_o x2[n][o] * W2[h][o][c] ----------------
__global__ __launch_bounds__(256) void k_gemm2(const float* __restrict__ x2,
                                               const float* __restrict__ W2,
                                               float* __restrict__ Wh2) {
    int t = blockIdx.x * blockDim.x + threadIdx.x;
    if (t >= NH * NN * NC) return;
    int c = t % NC;
    int n = (t / NC) % NN;
    int h = t / (NC * NN);
    const float* xp = x2 + (size_t)n * HIDN;
    const float* wp = W2 + ((size_t)h * HIDN) * NC + c;
    float acc = 0.f;
#pragma unroll
    for (int o = 0; o < HIDN; o++) acc += xp[o] * wp[(size_t)o * NC];
    Wh2[t] = acc;
}

// ---------------- e_src/e_dst for layer 2: one wave per (h,n), lane = c (<40) ----------------
__global__ __launch_bounds__(256) void k_e2(const float* __restrict__ Wh2,
                                            const float* __restrict__ a_src,
                                            const float* __restrict__ a_dst,
                                            float* __restrict__ es,
                                            float* __restrict__ ed) {
    int gw   = blockIdx.x * 4 + (threadIdx.x >> 6);
    int lane = threadIdx.x & 63;
    int h = gw / NN, n = gw % NN;
    float v = (lane < NC) ? Wh2[((size_t)h * NN + n) * NC + lane] : 0.f;
    float s = (lane < NC) ? v * a_src[h * NC + lane] : 0.f;
    float d = (lane < NC) ? v * a_dst[h * NC + lane] : 0.f;
#pragma unroll
    for (int off = 32; off; off >>= 1) {
        s += __shfl_xor(s, off);
        d += __shfl_xor(d, off);
    }
    if (lane == 0) { es[h * NN + n] = s; ed[h * NN + n] = d; }
}

// ---------------- Layer-2 attention + aggregate + head-mean + log_softmax ----------------
__global__ __launch_bounds__(64) void k_attn2(const int* __restrict__ nbr,
                                              const int* __restrict__ deg,
                                              const float* __restrict__ Wh2,
                                              const float* __restrict__ es,
                                              const float* __restrict__ ed,
                                              float* __restrict__ out) {
    int n = blockIdx.x;
    int lane = threadIdx.x;
    int d = deg[n];
    const int* nrow = nbr + (size_t)n * CAP;
    float acc = 0.f;
    for (int h = 0; h < NH; h++) {
        float esv = es[h * NN + n];
        float sv[NCHUNK]; int mv[NCHUNK];
        float mx = -INFINITY;
#pragma unroll
        for (int c = 0; c < NCHUNK; c++) {
            int k = c * 64 + lane;
            float s = -INFINITY; int mm = 0;
            if (k < d) {
                mm = nrow[k];
                float e = esv + ed[h * NN + mm];
                s = e > 0.f ? e : LALPHA * e;
            }
            sv[c] = s; mv[c] = mm;
            mx = fmaxf(mx, s);
        }
#pragma unroll
        for (int off = 32; off; off >>= 1) mx = fmaxf(mx, __shfl_xor(mx, off));
        float pv[NCHUNK]; float psum = 0.f;
#pragma unroll
        for (int c = 0; c < NCHUNK; c++) {
            int k = c * 64 + lane;
            float p = (k < d) ? __expf(sv[c] - mx) : 0.f;
            pv[c] = p; psum += p;
        }
#pragma unroll
        for (int off = 32; off; off >>= 1) psum += __shfl_xor(psum, off);
        float inv = 1.f / psum;
        float hacc = 0.f;
        for (int c = 0; c < NCHUNK; c++) {
            int kbase = c * 64;
            if (kbase >= d) break;
            int cnt = min(64, d - kbase);
            for (int j = 0; j < cnt; j++) {
                float p  = __shfl(pv[c], j);
                int   mm = __shfl(mv[c], j);
                if (lane < NC) hacc += p * Wh2[((size_t)h * NN + mm) * NC + lane];
            }
        }
        acc += hacc * inv;
    }
    acc *= (1.f / NH);
    // log_softmax across lanes 0..NC-1
    float v = (lane < NC) ? acc : -INFINITY;
    float mx2 = v;
#pragma unroll
    for (int off = 32; off; off >>= 1) mx2 = fmaxf(mx2, __shfl_xor(mx2, off));
    float ex = (lane < NC) ? __expf(acc - mx2) : 0.f;
    float se = ex;
#pragma unroll
    for (int off = 32; off; off >>= 1) se += __shfl_xor(se, off);
    if (lane < NC) out[(size_t)n * NC + lane] = acc - mx2 - logf(se);
}

extern "C" void kernel_launch(void* const* d_in, const int* in_sizes, int n_in,
                              void* d_out, int out_size, void* d_ws, size_t ws_size,
                              hipStream_t stream) {
    const float* feature = (const float*)d_in[0];
    const float* adj     = (const float*)d_in[1];
    const float* W1      = (const float*)d_in[2];
    const float* a1_src  = (const float*)d_in[3];
    const float* a1_dst  = (const float*)d_in[4];
    const float* W2      = (const float*)d_in[5];
    const float* a2_src  = (const float*)d_in[6];
    const float* a2_dst  = (const float*)d_in[7];
    float* out = (float*)d_out;

    char* ws = (char*)d_ws;
    size_t off = 0;
    int*   nbr = (int*)(ws + off);   off += (size_t)NN * CAP * sizeof(int);
    int*   deg = (int*)(ws + off);   off += (size_t)NN * sizeof(int);
    float* Wh1 = (float*)(ws + off); off += (size_t)NH * NN * HIDN * sizeof(float);
    float* e1s = (float*)(ws + off); off += (size_t)NH * NN * sizeof(float);
    float* e1d = (float*)(ws + off); off += (size_t)NH * NN * sizeof(float);
    float* x2  = (float*)(ws + off); off += (size_t)NN * HIDN * sizeof(float);
    float* Wh2 = (float*)(ws + off); off += (size_t)NH * NN * NC * sizeof(float);
    float* e2s = (float*)(ws + off); off += (size_t)NH * NN * sizeof(float);
    float* e2d = (float*)(ws + off); off += (size_t)NH * NN * sizeof(float);

    k_csr<<<NN / 4, 256, 0, stream>>>(adj, nbr, deg);
    k_gemm1<<<dim3(NN / 16, NH), 256, 0, stream>>>(feature, W1, Wh1);
    k_e1<<<(NH * NN) / 4, 256, 0, stream>>>(Wh1, a1_src, a1_dst, e1s, e1d);
    k_attn1<<<NN, 64, 0, stream>>>(nbr, deg, Wh1, e1s, e1d, x2);
    k_gemm2<<<(NH * NN * NC + 255) / 256, 256, 0, stream>>>(x2, W2, Wh2);
    k_e2<<<(NH * NN) / 4, 256, 0, stream>>>(Wh2, a2_src, a2_dst, e2s, e2d);
    k_attn2<<<NN, 64, 0, stream>>>(nbr, deg, Wh2, e2s, e2d, out);
}

// Round 2
// 217.984 us; speedup vs baseline: 1.2813x; 1.2813x over previous
//
#include <hip/hip_runtime.h>
#include <math.h>

#define NN   6144
#define FIN  512
#define HIDN 64
#define NC   40
#define NH   3
#define CAP  128           // max neighbors kept (deg ~ 61 +/- 8, 128 is ~8.5 sigma)
#define NCHUNK (CAP / 64)
#define LALPHA 0.2f

// ---------------- CSR build: one wave per row, ballot compaction ----------------
__global__ __launch_bounds__(256) void k_csr(const float* __restrict__ adj,
                                             int* __restrict__ nbr,
                                             int* __restrict__ deg) {
    int row  = blockIdx.x * 4 + (threadIdx.x >> 6);
    int lane = threadIdx.x & 63;
    const float* arow = adj + (size_t)row * NN;
    int* nrow = nbr + (size_t)row * CAP;
    int cnt = 0;
    for (int base = 0; base < NN; base += 256) {
        float4 v = *reinterpret_cast<const float4*>(arow + base + lane * 4);
        float vv[4] = {v.x, v.y, v.z, v.w};
#pragma unroll
        for (int q = 0; q < 4; q++) {
            bool on = vv[q] > 0.0f;
            unsigned long long mask = __ballot(on);
            if (on) {
                int pos = cnt + __popcll(mask & ((1ull << lane) - 1ull));
                if (pos < CAP) nrow[pos] = base + lane * 4 + q;
            }
            cnt += __popcll(mask);
        }
    }
    if (lane == 0) deg[row] = cnt < CAP ? cnt : CAP;
}

// ---------------- Layer-1 GEMM (tiled): Wh1[h][n][o] = sum_f x[n][f] * W1[h][f][o] ----
// grid (NN/64, NH), block 256. Tile 64(m) x 64(o), K-step 64.
// Each thread: 4m x 4o accumulators. LDS rows padded to 68 floats (16B-aligned,
// 2-way bank aliasing only).
__global__ __launch_bounds__(256) void k_gemm1(const float* __restrict__ x,
                                               const float* __restrict__ W,
                                               float* __restrict__ Wh) {
    __shared__ float xs[64][68];   // [m][k]
    __shared__ float wsh[64][68];  // [k][o]
    int h  = blockIdx.y;
    int n0 = blockIdx.x * 64;
    int tid = threadIdx.x;
    int og4 = (tid & 15) * 4;      // o offset (4 cols)
    int mg4 = (tid >> 4) * 4;      // m offset (4 rows)

    float acc[4][4] = {{0.f}};

    const float* xbase0 = x + (size_t)n0 * FIN;
    const float* wbase0 = W + (size_t)h * FIN * HIDN;

    for (int k0 = 0; k0 < FIN; k0 += 64) {
        // stage x tile [64m][64k] and W tile [64k][64o]; 4 float4 each per thread
#pragma unroll
        for (int i = 0; i < 4; i++) {
            int l = tid + i * 256;
            int r = l >> 4;
            int c = (l & 15) * 4;
            *reinterpret_cast<float4*>(&xs[r][c]) =
                *reinterpret_cast<const float4*>(xbase0 + (size_t)r * FIN + k0 + c);
            *reinterpret_cast<float4*>(&wsh[r][c]) =
                *reinterpret_cast<const float4*>(wbase0 + (size_t)(k0 + r) * HIDN + c);
        }
        __syncthreads();

#pragma unroll 8
        for (int k = 0; k < 64; k += 4) {
            float4 xv[4], wv[4];
            xv[0] = *reinterpret_cast<const float4*>(&xs[mg4 + 0][k]);
            xv[1] = *reinterpret_cast<const float4*>(&xs[mg4 + 1][k]);
            xv[2] = *reinterpret_cast<const float4*>(&xs[mg4 + 2][k]);
            xv[3] = *reinterpret_cast<const float4*>(&xs[mg4 + 3][k]);
            wv[0] = *reinterpret_cast<const float4*>(&wsh[k + 0][og4]);
            wv[1] = *reinterpret_cast<const float4*>(&wsh[k + 1][og4]);
            wv[2] = *reinterpret_cast<const float4*>(&wsh[k + 2][og4]);
            wv[3] = *reinterpret_cast<const float4*>(&wsh[k + 3][og4]);
            const float* xf = reinterpret_cast<const float*>(xv); // xf[i*4+kk]
            const float* wf = reinterpret_cast<const float*>(wv); // wf[kk*4+j]
#pragma unroll
            for (int i = 0; i < 4; i++) {
#pragma unroll
                for (int kk = 0; kk < 4; kk++) {
                    float xval = xf[i * 4 + kk];
#pragma unroll
                    for (int j = 0; j < 4; j++)
                        acc[i][j] += xval * wf[kk * 4 + j];
                }
            }
        }
        __syncthreads();
    }

    float* outp = Wh + ((size_t)h * NN + n0 + mg4) * HIDN + og4;
#pragma unroll
    for (int i = 0; i < 4; i++) {
        float4 v = make_float4(acc[i][0], acc[i][1], acc[i][2], acc[i][3]);
        *reinterpret_cast<float4*>(outp + (size_t)i * HIDN) = v;
    }
}

// ---------------- e_src/e_dst for layer 1: one wave per (h,n), lane = o ----------------
__global__ __launch_bounds__(256) void k_e1(const float* __restrict__ Wh,
                                            const float* __restrict__ a_src,
                                            const float* __restrict__ a_dst,
                                            float* __restrict__ es,
                                            float* __restrict__ ed) {
    int gw   = blockIdx.x * 4 + (threadIdx.x >> 6);
    int lane = threadIdx.x & 63;
    int h = gw / NN, n = gw % NN;
    float v = Wh[((size_t)h * NN + n) * HIDN + lane];
    float s = v * a_src[h * HIDN + lane];
    float d = v * a_dst[h * HIDN + lane];
#pragma unroll
    for (int off = 32; off; off >>= 1) {
        s += __shfl_xor(s, off);
        d += __shfl_xor(d, off);
    }
    if (lane == 0) { es[h * NN + n] = s; ed[h * NN + n] = d; }
}

// ---------------- Layer-1 attention + aggregate + head-mean + ReLU ----------------
// one wave (64 thr) per node; lane = output channel o
__global__ __launch_bounds__(64) void k_attn1(const int* __restrict__ nbr,
                                              const int* __restrict__ deg,
                                              const float* __restrict__ Wh,
                                              const float* __restrict__ es,
                                              const float* __restrict__ ed,
                                              float* __restrict__ x2) {
    int n = blockIdx.x;
    int lane = threadIdx.x;
    int d = deg[n];
    const int* nrow = nbr + (size_t)n * CAP;
    float acc = 0.f;
    for (int h = 0; h < NH; h++) {
        float esv = es[h * NN + n];
        float sv[NCHUNK]; int mv[NCHUNK];
        float mx = -INFINITY;
#pragma unroll
        for (int c = 0; c < NCHUNK; c++) {
            int k = c * 64 + lane;
            float s = -INFINITY; int mm = 0;
            if (k < d) {
                mm = nrow[k];
                float e = esv + ed[h * NN + mm];
                s = e > 0.f ? e : LALPHA * e;
            }
            sv[c] = s; mv[c] = mm;
            mx = fmaxf(mx, s);
        }
#pragma unroll
        for (int off = 32; off; off >>= 1) mx = fmaxf(mx, __shfl_xor(mx, off));
        float pv[NCHUNK]; float psum = 0.f;
#pragma unroll
        for (int c = 0; c < NCHUNK; c++) {
            int k = c * 64 + lane;
            float p = (k < d) ? __expf(sv[c] - mx) : 0.f;
            pv[c] = p; psum += p;
        }
#pragma unroll
        for (int off = 32; off; off >>= 1) psum += __shfl_xor(psum, off);
        float inv = 1.f / psum;
        float hacc = 0.f;
        for (int c = 0; c < NCHUNK; c++) {
            int kbase = c * 64;
            if (kbase >= d) break;
            int cnt = min(64, d - kbase);
            for (int j = 0; j < cnt; j++) {
                float p  = __shfl(pv[c], j);
                int   mm = __shfl(mv[c], j);
                hacc += p * Wh[((size_t)h * NN + mm) * HIDN + lane];
            }
        }
        acc += hacc * inv;
    }
    x2[(size_t)n * HIDN + lane] = fmaxf(acc * (1.f / NH), 0.f);
}

// ---------------- Layer-2 GEMM: Wh2[h][n][c] = sum_o x2[n][o] * W2[h][o][c] ----------------
__global__ __launch_bounds__(256) void k_gemm2(const float* __restrict__ x2,
                                               const float* __restrict__ W2,
                                               float* __restrict__ Wh2) {
    int t = blockIdx.x * blockDim.x + threadIdx.x;
    if (t >= NH * NN * NC) return;
    int c = t % NC;
    int n = (t / NC) % NN;
    int h = t / (NC * NN);
    const float* xp = x2 + (size_t)n * HIDN;
    const float* wp = W2 + ((size_t)h * HIDN) * NC + c;
    float acc = 0.f;
#pragma unroll
    for (int o = 0; o < HIDN; o++) acc += xp[o] * wp[(size_t)o * NC];
    Wh2[t] = acc;
}

// ---------------- e_src/e_dst for layer 2: one wave per (h,n), lane = c (<40) ----------------
__global__ __launch_bounds__(256) void k_e2(const float* __restrict__ Wh2,
                                            const float* __restrict__ a_src,
                                            const float* __restrict__ a_dst,
                                            float* __restrict__ es,
                                            float* __restrict__ ed) {
    int gw   = blockIdx.x * 4 + (threadIdx.x >> 6);
    int lane = threadIdx.x & 63;
    int h = gw / NN, n = gw % NN;
    float v = (lane < NC) ? Wh2[((size_t)h * NN + n) * NC + lane] : 0.f;
    float s = (lane < NC) ? v * a_src[h * NC + lane] : 0.f;
    float d = (lane < NC) ? v * a_dst[h * NC + lane] : 0.f;
#pragma unroll
    for (int off = 32; off; off >>= 1) {
        s += __shfl_xor(s, off);
        d += __shfl_xor(d, off);
    }
    if (lane == 0) { es[h * NN + n] = s; ed[h * NN + n] = d; }
}

// ---------------- Layer-2 attention + aggregate + head-mean + log_softmax ----------------
__global__ __launch_bounds__(64) void k_attn2(const int* __restrict__ nbr,
                                              const int* __restrict__ deg,
                                              const float* __restrict__ Wh2,
                                              const float* __restrict__ es,
                                              const float* __restrict__ ed,
                                              float* __restrict__ out) {
    int n = blockIdx.x;
    int lane = threadIdx.x;
    int d = deg[n];
    const int* nrow = nbr + (size_t)n * CAP;
    float acc = 0.f;
    for (int h = 0; h < NH; h++) {
        float esv = es[h * NN + n];
        float sv[NCHUNK]; int mv[NCHUNK];
        float mx = -INFINITY;
#pragma unroll
        for (int c = 0; c < NCHUNK; c++) {
            int k = c * 64 + lane;
            float s = -INFINITY; int mm = 0;
            if (k < d) {
                mm = nrow[k];
                float e = esv + ed[h * NN + mm];
                s = e > 0.f ? e : LALPHA * e;
            }
            sv[c] = s; mv[c] = mm;
            mx = fmaxf(mx, s);
        }
#pragma unroll
        for (int off = 32; off; off >>= 1) mx = fmaxf(mx, __shfl_xor(mx, off));
        float pv[NCHUNK]; float psum = 0.f;
#pragma unroll
        for (int c = 0; c < NCHUNK; c++) {
            int k = c * 64 + lane;
            float p = (k < d) ? __expf(sv[c] - mx) : 0.f;
            pv[c] = p; psum += p;
        }
#pragma unroll
        for (int off = 32; off; off >>= 1) psum += __shfl_xor(psum, off);
        float inv = 1.f / psum;
        float hacc = 0.f;
        for (int c = 0; c < NCHUNK; c++) {
            int kbase = c * 64;
            if (kbase >= d) break;
            int cnt = min(64, d - kbase);
            for (int j = 0; j < cnt; j++) {
                float p  = __shfl(pv[c], j);
                int   mm = __shfl(mv[c], j);
                if (lane < NC) hacc += p * Wh2[((size_t)h * NN + mm) * NC + lane];
            }
        }
        acc += hacc * inv;
    }
    acc *= (1.f / NH);
    // log_softmax across lanes 0..NC-1
    float v = (lane < NC) ? acc : -INFINITY;
    float mx2 = v;
#pragma unroll
    for (int off = 32; off; off >>= 1) mx2 = fmaxf(mx2, __shfl_xor(mx2, off));
    float ex = (lane < NC) ? __expf(acc - mx2) : 0.f;
    float se = ex;
#pragma unroll
    for (int off = 32; off; off >>= 1) se += __shfl_xor(se, off);
    if (lane < NC) out[(size_t)n * NC + lane] = acc - mx2 - logf(se);
}

extern "C" void kernel_launch(void* const* d_in, const int* in_sizes, int n_in,
                              void* d_out, int out_size, void* d_ws, size_t ws_size,
                              hipStream_t stream) {
    const float* feature = (const float*)d_in[0];
    const float* adj     = (const float*)d_in[1];
    const float* W1      = (const float*)d_in[2];
    const float* a1_src  = (const float*)d_in[3];
    const float* a1_dst  = (const float*)d_in[4];
    const float* W2      = (const float*)d_in[5];
    const float* a2_src  = (const float*)d_in[6];
    const float* a2_dst  = (const float*)d_in[7];
    float* out = (float*)d_out;

    char* ws = (char*)d_ws;
    size_t off = 0;
    int*   nbr = (int*)(ws + off);   off += (size_t)NN * CAP * sizeof(int);
    int*   deg = (int*)(ws + off);   off += (size_t)NN * sizeof(int);
    float* Wh1 = (float*)(ws + off); off += (size_t)NH * NN * HIDN * sizeof(float);
    float* e1s = (float*)(ws + off); off += (size_t)NH * NN * sizeof(float);
    float* e1d = (float*)(ws + off); off += (size_t)NH * NN * sizeof(float);
    float* x2  = (float*)(ws + off); off += (size_t)NN * HIDN * sizeof(float);
    float* Wh2 = (float*)(ws + off); off += (size_t)NH * NN * NC * sizeof(float);
    float* e2s = (float*)(ws + off); off += (size_t)NH * NN * sizeof(float);
    float* e2d = (float*)(ws + off); off += (size_t)NH * NN * sizeof(float);

    k_csr<<<NN / 4, 256, 0, stream>>>(adj, nbr, deg);
    k_gemm1<<<dim3(NN / 64, NH), 256, 0, stream>>>(feature, W1, Wh1);
    k_e1<<<(NH * NN) / 4, 256, 0, stream>>>(Wh1, a1_src, a1_dst, e1s, e1d);
    k_attn1<<<NN, 64, 0, stream>>>(nbr, deg, Wh1, e1s, e1d, x2);
    k_gemm2<<<(NH * NN * NC + 255) / 256, 256, 0, stream>>>(x2, W2, Wh2);
    k_e2<<<(NH * NN) / 4, 256, 0, stream>>>(Wh2, a2_src, a2_dst, e2s, e2d);
    k_attn2<<<NN, 64, 0, stream>>>(nbr, deg, Wh2, e2s, e2d, out);
}

// Round 3
// 174.599 us; speedup vs baseline: 1.5997x; 1.2485x over previous
//
#include <hip/hip_runtime.h>
#include <math.h>

#define NN   6144
#define FIN  512
#define HIDN 64
#define NC   40
#define NH   3
#define CAP  128           // max neighbors kept (deg ~61 +/- 8; 128 ~ 8.5 sigma)
#define NCHUNK (CAP / 64)
#define LALPHA 0.2f
#define KSPLIT 4
#define PK_LOW  0x3FFFu
#define PK_HIGH 0xFFFFC000u

// ---------------- CSR build: one wave per row, ballot compaction ----------------
__global__ __launch_bounds__(256) void k_csr(const float* __restrict__ adj,
                                             int* __restrict__ nbr,
                                             int* __restrict__ deg) {
    int row  = blockIdx.x * 4 + (threadIdx.x >> 6);
    int lane = threadIdx.x & 63;
    const float* arow = adj + (size_t)row * NN;
    int* nrow = nbr + (size_t)row * CAP;
    int cnt = 0;
    for (int base = 0; base < NN; base += 256) {
        float4 v = *reinterpret_cast<const float4*>(arow + base + lane * 4);
        float vv[4] = {v.x, v.y, v.z, v.w};
#pragma unroll
        for (int q = 0; q < 4; q++) {
            bool on = vv[q] > 0.0f;
            unsigned long long mask = __ballot(on);
            if (on) {
                int pos = cnt + __popcll(mask & ((1ull << lane) - 1ull));
                if (pos < CAP) nrow[pos] = base + lane * 4 + q;
            }
            cnt += __popcll(mask);
        }
    }
    if (lane == 0) deg[row] = cnt < CAP ? cnt : CAP;
}

// ---------------- Layer-1 GEMM, K-split: partial[z] = x[:,kz] * W1[h][kz,:] ----------
// grid (NN/64, NH, KSPLIT), block 256. Tile 64m x 64o, K-chunk 128 (2 steps of 64).
__global__ __launch_bounds__(256) void k_gemm1(const float* __restrict__ x,
                                               const float* __restrict__ W,
                                               float* __restrict__ Whp) {
    __shared__ float xs[64][68];   // [m][k]
    __shared__ float wsh[64][68];  // [k][o]
    int h  = blockIdx.y;
    int n0 = blockIdx.x * 64;
    int kz = blockIdx.z;
    int tid = threadIdx.x;
    int og4 = (tid & 15) * 4;      // o offset (4 cols)
    int mg4 = (tid >> 4) * 4;      // m offset (4 rows)

    float acc[4][4] = {{0.f}};

    const float* xbase0 = x + (size_t)n0 * FIN;
    const float* wbase0 = W + (size_t)h * FIN * HIDN;

    for (int t = 0; t < 2; t++) {
        int k0 = kz * 128 + t * 64;
#pragma unroll
        for (int i = 0; i < 4; i++) {
            int l = tid + i * 256;
            int r = l >> 4;
            int c = (l & 15) * 4;
            *reinterpret_cast<float4*>(&xs[r][c]) =
                *reinterpret_cast<const float4*>(xbase0 + (size_t)r * FIN + k0 + c);
            *reinterpret_cast<float4*>(&wsh[r][c]) =
                *reinterpret_cast<const float4*>(wbase0 + (size_t)(k0 + r) * HIDN + c);
        }
        __syncthreads();

#pragma unroll 8
        for (int k = 0; k < 64; k += 4) {
            float4 xv[4], wv[4];
            xv[0] = *reinterpret_cast<const float4*>(&xs[mg4 + 0][k]);
            xv[1] = *reinterpret_cast<const float4*>(&xs[mg4 + 1][k]);
            xv[2] = *reinterpret_cast<const float4*>(&xs[mg4 + 2][k]);
            xv[3] = *reinterpret_cast<const float4*>(&xs[mg4 + 3][k]);
            wv[0] = *reinterpret_cast<const float4*>(&wsh[k + 0][og4]);
            wv[1] = *reinterpret_cast<const float4*>(&wsh[k + 1][og4]);
            wv[2] = *reinterpret_cast<const float4*>(&wsh[k + 2][og4]);
            wv[3] = *reinterpret_cast<const float4*>(&wsh[k + 3][og4]);
            const float* xf = reinterpret_cast<const float*>(xv);
            const float* wf = reinterpret_cast<const float*>(wv);
#pragma unroll
            for (int i = 0; i < 4; i++) {
#pragma unroll
                for (int kk = 0; kk < 4; kk++) {
                    float xval = xf[i * 4 + kk];
#pragma unroll
                    for (int j = 0; j < 4; j++)
                        acc[i][j] += xval * wf[kk * 4 + j];
                }
            }
        }
        __syncthreads();
    }

    float* outp = Whp + (((size_t)kz * NH + h) * NN + n0 + mg4) * HIDN + og4;
#pragma unroll
    for (int i = 0; i < 4; i++) {
        float4 v = make_float4(acc[i][0], acc[i][1], acc[i][2], acc[i][3]);
        *reinterpret_cast<float4*>(outp + (size_t)i * HIDN) = v;
    }
}

// ---------------- sum K-split partials -> Wh1, and compute es/ed ----------------
__global__ __launch_bounds__(256) void k_sum_e1(const float* __restrict__ Whp,
                                                const float* __restrict__ a_src,
                                                const float* __restrict__ a_dst,
                                                float* __restrict__ Wh,
                                                float* __restrict__ es,
                                                float* __restrict__ ed) {
    int gw   = blockIdx.x * 4 + (threadIdx.x >> 6);
    int lane = threadIdx.x & 63;
    int h = gw / NN, n = gw % NN;
    size_t idx = ((size_t)h * NN + n) * HIDN + lane;
    size_t stride = (size_t)NH * NN * HIDN;
    float v = Whp[idx] + Whp[idx + stride] + Whp[idx + 2 * stride] + Whp[idx + 3 * stride];
    Wh[idx] = v;
    float s = v * a_src[h * HIDN + lane];
    float d = v * a_dst[h * HIDN + lane];
#pragma unroll
    for (int off = 32; off; off >>= 1) {
        s += __shfl_xor(s, off);
        d += __shfl_xor(d, off);
    }
    if (lane == 0) { es[h * NN + n] = s; ed[h * NN + n] = d; }
}

// ---------------- Layer-1 attention + head-mean + ReLU + layer-2 GEMM + e2 --------
// block = 192 (3 waves, wave h = head h); grid = NN
__global__ __launch_bounds__(192) void k_attn1f(const int* __restrict__ nbr,
                                                const int* __restrict__ deg,
                                                const float* __restrict__ Wh,
                                                const float* __restrict__ es,
                                                const float* __restrict__ ed,
                                                const float* __restrict__ W2,
                                                const float* __restrict__ a2s,
                                                const float* __restrict__ a2d,
                                                float* __restrict__ Wh2,
                                                float* __restrict__ e2s,
                                                float* __restrict__ e2d) {
    __shared__ float hsum[NH][HIDN];
    int n = blockIdx.x;
    int h = threadIdx.x >> 6;
    int lane = threadIdx.x & 63;
    int d = deg[n];
    const int* nrow = nbr + (size_t)n * CAP;
    float esv = es[h * NN + n];

    unsigned pk[NCHUNK];
    float psum = 0.f;
#pragma unroll
    for (int c = 0; c < NCHUNK; c++) {
        int k = c * 64 + lane;
        unsigned u = 0;
        if (k < d) {
            int mm = nrow[k];
            float e = esv + ed[h * NN + mm];
            float s = e > 0.f ? e : LALPHA * e;
            float p = __expf(s);
            u = (__float_as_uint(p) & PK_HIGH) | (unsigned)mm;
            psum += __uint_as_float(u & PK_HIGH);
        }
        pk[c] = u;
    }
#pragma unroll
    for (int off = 32; off; off >>= 1) psum += __shfl_xor(psum, off);
    float inv = 1.f / psum;

    float hacc = 0.f;
    for (int c = 0; c < NCHUNK; c++) {
        int kbase = c * 64;
        if (kbase >= d) break;
        int cnt = min(64, d - kbase);
        for (int j = 0; j < cnt; j++) {
            unsigned u = __shfl(pk[c], j);
            int   mm = (int)(u & PK_LOW);
            float p  = __uint_as_float(u & PK_HIGH);
            hacc += p * Wh[((size_t)h * NN + mm) * HIDN + lane];
        }
    }
    hsum[h][lane] = hacc * inv;
    __syncthreads();

    // every wave computes the x2 row value for its lane (identical across waves)
    float xv = (hsum[0][lane] + hsum[1][lane] + hsum[2][lane]) * (1.f / NH);
    xv = fmaxf(xv, 0.f);

    // layer-2 linear for head h: Wh2[h][n][c] = sum_o x2[o] * W2[h][o][c]
    int c = lane < NC ? lane : NC - 1;
    float acc = 0.f;
#pragma unroll 8
    for (int o = 0; o < HIDN; o++) {
        float xb = __shfl(xv, o);
        float wv = W2[((size_t)h * HIDN + o) * NC + c];
        acc += xb * wv;
    }
    if (lane >= NC) acc = 0.f;

    float s2 = acc * (lane < NC ? a2s[h * NC + lane] : 0.f);
    float d2 = acc * (lane < NC ? a2d[h * NC + lane] : 0.f);
#pragma unroll
    for (int off = 32; off; off >>= 1) {
        s2 += __shfl_xor(s2, off);
        d2 += __shfl_xor(d2, off);
    }
    if (lane < NC) Wh2[((size_t)h * NN + n) * NC + lane] = acc;
    if (lane == 0) { e2s[h * NN + n] = s2; e2d[h * NN + n] = d2; }
}

// ---------------- Layer-2 attention + head-mean + log_softmax ----------------
__global__ __launch_bounds__(192) void k_attn2(const int* __restrict__ nbr,
                                               const int* __restrict__ deg,
                                               const float* __restrict__ Wh2,
                                               const float* __restrict__ es,
                                               const float* __restrict__ ed,
                                               float* __restrict__ out) {
    __shared__ float hsum[NH][HIDN];
    int n = blockIdx.x;
    int h = threadIdx.x >> 6;
    int lane = threadIdx.x & 63;
    int d = deg[n];
    const int* nrow = nbr + (size_t)n * CAP;
    float esv = es[h * NN + n];

    unsigned pk[NCHUNK];
    float psum = 0.f;
#pragma unroll
    for (int c = 0; c < NCHUNK; c++) {
        int k = c * 64 + lane;
        unsigned u = 0;
        if (k < d) {
            int mm = nrow[k];
            float e = esv + ed[h * NN + mm];
            float s = e > 0.f ? e : LALPHA * e;
            float p = __expf(s);
            u = (__float_as_uint(p) & PK_HIGH) | (unsigned)mm;
            psum += __uint_as_float(u & PK_HIGH);
        }
        pk[c] = u;
    }
#pragma unroll
    for (int off = 32; off; off >>= 1) psum += __shfl_xor(psum, off);
    float inv = 1.f / psum;

    float hacc = 0.f;
    for (int c = 0; c < NCHUNK; c++) {
        int kbase = c * 64;
        if (kbase >= d) break;
        int cnt = min(64, d - kbase);
        for (int j = 0; j < cnt; j++) {
            unsigned u = __shfl(pk[c], j);
            int   mm = (int)(u & PK_LOW);
            float p  = __uint_as_float(u & PK_HIGH);
            if (lane < NC) hacc += p * Wh2[((size_t)h * NN + mm) * NC + lane];
        }
    }
    if (lane < NC) hsum[h][lane] = hacc * inv;
    __syncthreads();

    if (threadIdx.x < 64) {
        float a = (lane < NC)
            ? (hsum[0][lane] + hsum[1][lane] + hsum[2][lane]) * (1.f / NH)
            : -INFINITY;
        float mx = a;
#pragma unroll
        for (int off = 32; off; off >>= 1) mx = fmaxf(mx, __shfl_xor(mx, off));
        float ex = (lane < NC) ? __expf(a - mx) : 0.f;
        float se = ex;
#pragma unroll
        for (int off = 32; off; off >>= 1) se += __shfl_xor(se, off);
        if (lane < NC) out[(size_t)n * NC + lane] = a - mx - logf(se);
    }
}

extern "C" void kernel_launch(void* const* d_in, const int* in_sizes, int n_in,
                              void* d_out, int out_size, void* d_ws, size_t ws_size,
                              hipStream_t stream) {
    const float* feature = (const float*)d_in[0];
    const float* adj     = (const float*)d_in[1];
    const float* W1      = (const float*)d_in[2];
    const float* a1_src  = (const float*)d_in[3];
    const float* a1_dst  = (const float*)d_in[4];
    const float* W2      = (const float*)d_in[5];
    const float* a2_src  = (const float*)d_in[6];
    const float* a2_dst  = (const float*)d_in[7];
    float* out = (float*)d_out;

    char* ws = (char*)d_ws;
    size_t off = 0;
    int*   nbr = (int*)(ws + off);   off += (size_t)NN * CAP * sizeof(int);
    int*   deg = (int*)(ws + off);   off += (size_t)NN * sizeof(int);
    float* Whp = (float*)(ws + off); off += (size_t)KSPLIT * NH * NN * HIDN * sizeof(float);
    float* Wh1 = (float*)(ws + off); off += (size_t)NH * NN * HIDN * sizeof(float);
    float* e1s = (float*)(ws + off); off += (size_t)NH * NN * sizeof(float);
    float* e1d = (float*)(ws + off); off += (size_t)NH * NN * sizeof(float);
    float* Wh2 = (float*)(ws + off); off += (size_t)NH * NN * NC * sizeof(float);
    float* e2s = (float*)(ws + off); off += (size_t)NH * NN * sizeof(float);
    float* e2d = (float*)(ws + off); off += (size_t)NH * NN * sizeof(float);

    k_csr<<<NN / 4, 256, 0, stream>>>(adj, nbr, deg);
    k_gemm1<<<dim3(NN / 64, NH, KSPLIT), 256, 0, stream>>>(feature, W1, Whp);
    k_sum_e1<<<(NH * NN) / 4, 256, 0, stream>>>(Whp, a1_src, a1_dst, Wh1, e1s, e1d);
    k_attn1f<<<NN, 192, 0, stream>>>(nbr, deg, Wh1, e1s, e1d, W2, a2_src, a2_dst,
                                     Wh2, e2s, e2d);
    k_attn2<<<NN, 192, 0, stream>>>(nbr, deg, Wh2, e2s, e2d, out);
}

// Round 4
// 105.867 us; speedup vs baseline: 2.6383x; 1.6492x over previous
//
#include <hip/hip_runtime.h>
#include <math.h>

#define NN   6144
#define FIN  512
#define HIDN 64
#define NC   40
#define NH   3
#define CAP  128           // max neighbors kept (deg ~61 +/- 8; 128 ~ 8.5 sigma)
#define NCHUNK (CAP / 64)
#define LALPHA 0.2f
#define KSPLIT 4
#define PK_LOW  0x3FFFu
#define PK_HIGH 0xFFFFC000u

// ---------------- CSR build: one wave per row, ballot compaction ----------------
__global__ __launch_bounds__(256) void k_csr(const float* __restrict__ adj,
                                             int* __restrict__ nbr,
                                             int* __restrict__ deg) {
    int row  = blockIdx.x * 4 + (threadIdx.x >> 6);
    int lane = threadIdx.x & 63;
    const float* arow = adj + (size_t)row * NN;
    int* nrow = nbr + (size_t)row * CAP;
    int cnt = 0;
    for (int base = 0; base < NN; base += 256) {
        float4 v = *reinterpret_cast<const float4*>(arow + base + lane * 4);
        float vv[4] = {v.x, v.y, v.z, v.w};
#pragma unroll
        for (int q = 0; q < 4; q++) {
            bool on = vv[q] > 0.0f;
            unsigned long long mask = __ballot(on);
            if (on) {
                int pos = cnt + __popcll(mask & ((1ull << lane) - 1ull));
                if (pos < CAP) nrow[pos] = base + lane * 4 + q;
            }
            cnt += __popcll(mask);
        }
    }
    if (lane == 0) deg[row] = cnt < CAP ? cnt : CAP;
}

// ---------------- Layer-1 GEMM, K-split: partial[z] = x[:,kz] * W1[h][kz,:] ----------
__global__ __launch_bounds__(256) void k_gemm1(const float* __restrict__ x,
                                               const float* __restrict__ W,
                                               float* __restrict__ Whp) {
    __shared__ float xs[64][68];   // [m][k]
    __shared__ float wsh[64][68];  // [k][o]
    int h  = blockIdx.y;
    int n0 = blockIdx.x * 64;
    int kz = blockIdx.z;
    int tid = threadIdx.x;
    int og4 = (tid & 15) * 4;      // o offset (4 cols)
    int mg4 = (tid >> 4) * 4;      // m offset (4 rows)

    float acc[4][4] = {{0.f}};

    const float* xbase0 = x + (size_t)n0 * FIN;
    const float* wbase0 = W + (size_t)h * FIN * HIDN;

    for (int t = 0; t < 2; t++) {
        int k0 = kz * 128 + t * 64;
#pragma unroll
        for (int i = 0; i < 4; i++) {
            int l = tid + i * 256;
            int r = l >> 4;
            int c = (l & 15) * 4;
            *reinterpret_cast<float4*>(&xs[r][c]) =
                *reinterpret_cast<const float4*>(xbase0 + (size_t)r * FIN + k0 + c);
            *reinterpret_cast<float4*>(&wsh[r][c]) =
                *reinterpret_cast<const float4*>(wbase0 + (size_t)(k0 + r) * HIDN + c);
        }
        __syncthreads();

#pragma unroll 8
        for (int k = 0; k < 64; k += 4) {
            float4 xv[4], wv[4];
            xv[0] = *reinterpret_cast<const float4*>(&xs[mg4 + 0][k]);
            xv[1] = *reinterpret_cast<const float4*>(&xs[mg4 + 1][k]);
            xv[2] = *reinterpret_cast<const float4*>(&xs[mg4 + 2][k]);
            xv[3] = *reinterpret_cast<const float4*>(&xs[mg4 + 3][k]);
            wv[0] = *reinterpret_cast<const float4*>(&wsh[k + 0][og4]);
            wv[1] = *reinterpret_cast<const float4*>(&wsh[k + 1][og4]);
            wv[2] = *reinterpret_cast<const float4*>(&wsh[k + 2][og4]);
            wv[3] = *reinterpret_cast<const float4*>(&wsh[k + 3][og4]);
            const float* xf = reinterpret_cast<const float*>(xv);
            const float* wf = reinterpret_cast<const float*>(wv);
#pragma unroll
            for (int i = 0; i < 4; i++) {
#pragma unroll
                for (int kk = 0; kk < 4; kk++) {
                    float xval = xf[i * 4 + kk];
#pragma unroll
                    for (int j = 0; j < 4; j++)
                        acc[i][j] += xval * wf[kk * 4 + j];
                }
            }
        }
        __syncthreads();
    }

    float* outp = Whp + (((size_t)kz * NH + h) * NN + n0 + mg4) * HIDN + og4;
#pragma unroll
    for (int i = 0; i < 4; i++) {
        float4 v = make_float4(acc[i][0], acc[i][1], acc[i][2], acc[i][3]);
        *reinterpret_cast<float4*>(outp + (size_t)i * HIDN) = v;
    }
}

// ---------------- sum K-split partials -> Wh1, and compute es/ed ----------------
__global__ __launch_bounds__(256) void k_sum_e1(const float* __restrict__ Whp,
                                                const float* __restrict__ a_src,
                                                const float* __restrict__ a_dst,
                                                float* __restrict__ Wh,
                                                float* __restrict__ es,
                                                float* __restrict__ ed) {
    int gw   = blockIdx.x * 4 + (threadIdx.x >> 6);
    int lane = threadIdx.x & 63;
    int h = gw / NN, n = gw % NN;
    size_t idx = ((size_t)h * NN + n) * HIDN + lane;
    size_t stride = (size_t)NH * NN * HIDN;
    float v = Whp[idx] + Whp[idx + stride] + Whp[idx + 2 * stride] + Whp[idx + 3 * stride];
    Wh[idx] = v;
    float s = v * a_src[h * HIDN + lane];
    float d = v * a_dst[h * HIDN + lane];
#pragma unroll
    for (int off = 32; off; off >>= 1) {
        s += __shfl_xor(s, off);
        d += __shfl_xor(d, off);
    }
    if (lane == 0) { es[h * NN + n] = s; ed[h * NN + n] = d; }
}

// ---------------- Layer-1 attention + head-mean + ReLU + layer-2 GEMM + e2 --------
// block = 192 (3 waves, wave h = head h); grid = NN
__global__ __launch_bounds__(192) void k_attn1f(const int* __restrict__ nbr,
                                                const int* __restrict__ deg,
                                                const float* __restrict__ Wh,
                                                const float* __restrict__ es,
                                                const float* __restrict__ ed,
                                                const float* __restrict__ W2,
                                                const float* __restrict__ a2s,
                                                const float* __restrict__ a2d,
                                                float* __restrict__ Wh2,
                                                float* __restrict__ e2s,
                                                float* __restrict__ e2d) {
    __shared__ unsigned pks[NH][CAP];
    __shared__ float hsum[NH][HIDN];
    int n = blockIdx.x;
    int h = threadIdx.x >> 6;
    int lane = threadIdx.x & 63;
    int d = deg[n];
    const int* nrow = nbr + (size_t)n * CAP;
    float esv = es[h * NN + n];

    float psum = 0.f;
#pragma unroll
    for (int c = 0; c < NCHUNK; c++) {
        int k = c * 64 + lane;
        unsigned u = 0;
        if (k < d) {
            int mm = nrow[k];
            float e = esv + ed[h * NN + mm];
            float s = e > 0.f ? e : LALPHA * e;
            float p = __expf(s);
            u = (__float_as_uint(p) & PK_HIGH) | (unsigned)mm;
            psum += __uint_as_float(u & PK_HIGH);
        }
        pks[h][k] = u;
    }
#pragma unroll
    for (int off = 32; off; off >>= 1) psum += __shfl_xor(psum, off);
    float inv = 1.f / psum;
    __syncthreads();

    // aggregate 4 neighbors / iter: 1 ds_read_b128 broadcast + 4 indep load->FMA chains
    const float* WhH = Wh + (size_t)h * NN * HIDN + lane;
    float a0 = 0.f, a1 = 0.f, a2 = 0.f, a3 = 0.f;
    int iters = (d + 3) >> 2;
    for (int g = 0; g < iters; g++) {
        uint4 uu = *reinterpret_cast<const uint4*>(&pks[h][g * 4]);
        a0 += __uint_as_float(uu.x & PK_HIGH) * WhH[(size_t)(uu.x & PK_LOW) * HIDN];
        a1 += __uint_as_float(uu.y & PK_HIGH) * WhH[(size_t)(uu.y & PK_LOW) * HIDN];
        a2 += __uint_as_float(uu.z & PK_HIGH) * WhH[(size_t)(uu.z & PK_LOW) * HIDN];
        a3 += __uint_as_float(uu.w & PK_HIGH) * WhH[(size_t)(uu.w & PK_LOW) * HIDN];
    }
    float hacc = ((a0 + a1) + (a2 + a3));
    hsum[h][lane] = hacc * inv;
    __syncthreads();

    // every wave computes the x2 row value for its lane (identical across waves)
    float xv = (hsum[0][lane] + hsum[1][lane] + hsum[2][lane]) * (1.f / NH);
    xv = fmaxf(xv, 0.f);

    // layer-2 linear for head h: Wh2[h][n][c] = sum_o x2[o] * W2[h][o][c]
    int c = lane < NC ? lane : NC - 1;
    float acc = 0.f;
#pragma unroll 8
    for (int o = 0; o < HIDN; o++) {
        float xb = __shfl(xv, o);
        float wv = W2[((size_t)h * HIDN + o) * NC + c];
        acc += xb * wv;
    }
    if (lane >= NC) acc = 0.f;

    float s2 = acc * (lane < NC ? a2s[h * NC + lane] : 0.f);
    float d2 = acc * (lane < NC ? a2d[h * NC + lane] : 0.f);
#pragma unroll
    for (int off = 32; off; off >>= 1) {
        s2 += __shfl_xor(s2, off);
        d2 += __shfl_xor(d2, off);
    }
    if (lane < NC) Wh2[((size_t)h * NN + n) * NC + lane] = acc;
    if (lane == 0) { e2s[h * NN + n] = s2; e2d[h * NN + n] = d2; }
}

// ---------------- Layer-2 attention + head-mean + log_softmax ----------------
__global__ __launch_bounds__(192) void k_attn2(const int* __restrict__ nbr,
                                               const int* __restrict__ deg,
                                               const float* __restrict__ Wh2,
                                               const float* __restrict__ es,
                                               const float* __restrict__ ed,
                                               float* __restrict__ out) {
    __shared__ unsigned pks[NH][CAP];
    __shared__ float hsum[NH][HIDN];
    int n = blockIdx.x;
    int h = threadIdx.x >> 6;
    int lane = threadIdx.x & 63;
    int d = deg[n];
    const int* nrow = nbr + (size_t)n * CAP;
    float esv = es[h * NN + n];

    float psum = 0.f;
#pragma unroll
    for (int c = 0; c < NCHUNK; c++) {
        int k = c * 64 + lane;
        unsigned u = 0;
        if (k < d) {
            int mm = nrow[k];
            float e = esv + ed[h * NN + mm];
            float s = e > 0.f ? e : LALPHA * e;
            float p = __expf(s);
            u = (__float_as_uint(p) & PK_HIGH) | (unsigned)mm;
            psum += __uint_as_float(u & PK_HIGH);
        }
        pks[h][k] = u;
    }
#pragma unroll
    for (int off = 32; off; off >>= 1) psum += __shfl_xor(psum, off);
    float inv = 1.f / psum;
    __syncthreads();

    const float* W2H = Wh2 + (size_t)h * NN * NC + (lane < NC ? lane : 0);
    float a0 = 0.f, a1 = 0.f, a2 = 0.f, a3 = 0.f;
    int iters = (d + 3) >> 2;
    for (int g = 0; g < iters; g++) {
        uint4 uu = *reinterpret_cast<const uint4*>(&pks[h][g * 4]);
        a0 += __uint_as_float(uu.x & PK_HIGH) * W2H[(size_t)(uu.x & PK_LOW) * NC];
        a1 += __uint_as_float(uu.y & PK_HIGH) * W2H[(size_t)(uu.y & PK_LOW) * NC];
        a2 += __uint_as_float(uu.z & PK_HIGH) * W2H[(size_t)(uu.z & PK_LOW) * NC];
        a3 += __uint_as_float(uu.w & PK_HIGH) * W2H[(size_t)(uu.w & PK_LOW) * NC];
    }
    float hacc = ((a0 + a1) + (a2 + a3));
    if (lane < NC) hsum[h][lane] = hacc * inv;
    __syncthreads();

    if (threadIdx.x < 64) {
        float a = (lane < NC)
            ? (hsum[0][lane] + hsum[1][lane] + hsum[2][lane]) * (1.f / NH)
            : -INFINITY;
        float mx = a;
#pragma unroll
        for (int off = 32; off; off >>= 1) mx = fmaxf(mx, __shfl_xor(mx, off));
        float ex = (lane < NC) ? __expf(a - mx) : 0.f;
        float se = ex;
#pragma unroll
        for (int off = 32; off; off >>= 1) se += __shfl_xor(se, off);
        if (lane < NC) out[(size_t)n * NC + lane] = a - mx - logf(se);
    }
}

extern "C" void kernel_launch(void* const* d_in, const int* in_sizes, int n_in,
                              void* d_out, int out_size, void* d_ws, size_t ws_size,
                              hipStream_t stream) {
    const float* feature = (const float*)d_in[0];
    const float* adj     = (const float*)d_in[1];
    const float* W1      = (const float*)d_in[2];
    const float* a1_src  = (const float*)d_in[3];
    const float* a1_dst  = (const float*)d_in[4];
    const float* W2      = (const float*)d_in[5];
    const float* a2_src  = (const float*)d_in[6];
    const float* a2_dst  = (const float*)d_in[7];
    float* out = (float*)d_out;

    char* ws = (char*)d_ws;
    size_t off = 0;
    int*   nbr = (int*)(ws + off);   off += (size_t)NN * CAP * sizeof(int);
    int*   deg = (int*)(ws + off);   off += (size_t)NN * sizeof(int);
    float* Whp = (float*)(ws + off); off += (size_t)KSPLIT * NH * NN * HIDN * sizeof(float);
    float* Wh1 = (float*)(ws + off); off += (size_t)NH * NN * HIDN * sizeof(float);
    float* e1s = (float*)(ws + off); off += (size_t)NH * NN * sizeof(float);
    float* e1d = (float*)(ws + off); off += (size_t)NH * NN * sizeof(float);
    float* Wh2 = (float*)(ws + off); off += (size_t)NH * NN * NC * sizeof(float);
    float* e2s = (float*)(ws + off); off += (size_t)NH * NN * sizeof(float);
    float* e2d = (float*)(ws + off); off += (size_t)NH * NN * sizeof(float);

    k_csr<<<NN / 4, 256, 0, stream>>>(adj, nbr, deg);
    k_gemm1<<<dim3(NN / 64, NH, KSPLIT), 256, 0, stream>>>(feature, W1, Whp);
    k_sum_e1<<<(NH * NN) / 4, 256, 0, stream>>>(Whp, a1_src, a1_dst, Wh1, e1s, e1d);
    k_attn1f<<<NN, 192, 0, stream>>>(nbr, deg, Wh1, e1s, e1d, W2, a2_src, a2_dst,
                                     Wh2, e2s, e2d);
    k_attn2<<<NN, 192, 0, stream>>>(nbr, deg, Wh2, e2s, e2d, out);
}

// Round 5
// 102.578 us; speedup vs baseline: 2.7228x; 1.0321x over previous
//
#include <hip/hip_runtime.h>
#include <math.h>

#define NN   6144
#define FIN  512
#define HIDN 64
#define NC   40
#define NH   3
#define CAP  128           // max neighbors kept (deg ~61 +/- 8; 128 ~ 8.5 sigma)
#define NCHUNK (CAP / 64)
#define LALPHA 0.2f
#define KSPLIT 4
#define PK_LOW  0x3FFFu
#define PK_HIGH 0xFFFFC000u
#define CSRB   (NN / 4)                    // 1536 csr blocks
#define GEMMB  ((NN / 64) * NH * KSPLIT)   // 1152 gemm blocks

__device__ __forceinline__ float bf2f(ushort s) {
    return __uint_as_float((unsigned)s << 16);
}
__device__ __forceinline__ ushort f2bf(float f) {
    unsigned u = __float_as_uint(f);
    return (ushort)((u + 0x7FFFu + ((u >> 16) & 1u)) >> 16);   // RNE
}

// ---------------- fused: CSR build (blocks [0,CSRB)) + layer-1 GEMM (rest) ----------
__global__ __launch_bounds__(256) void k_csr_gemm(const float* __restrict__ adj,
                                                  int* __restrict__ nbr,
                                                  int* __restrict__ deg,
                                                  const float* __restrict__ x,
                                                  const float* __restrict__ W,
                                                  float* __restrict__ Whp) {
    __shared__ float smem[2 * 64 * 68];
    int bid = blockIdx.x;
    int tid = threadIdx.x;

    if (bid < CSRB) {
        // ---- CSR: one wave per row, ballot compaction ----
        int row  = bid * 4 + (tid >> 6);
        int lane = tid & 63;
        const float* arow = adj + (size_t)row * NN;
        int* nrow = nbr + (size_t)row * CAP;
        int cnt = 0;
        for (int base = 0; base < NN; base += 256) {
            float4 v = *reinterpret_cast<const float4*>(arow + base + lane * 4);
            float vv[4] = {v.x, v.y, v.z, v.w};
#pragma unroll
            for (int q = 0; q < 4; q++) {
                bool on = vv[q] > 0.0f;
                unsigned long long mask = __ballot(on);
                if (on) {
                    int pos = cnt + __popcll(mask & ((1ull << lane) - 1ull));
                    if (pos < CAP) nrow[pos] = base + lane * 4 + q;
                }
                cnt += __popcll(mask);
            }
        }
        if (lane == 0) deg[row] = cnt < CAP ? cnt : CAP;
        return;
    }

    // ---- GEMM: tile 64m x 64o, K-chunk 128 ----
    int b  = bid - CSRB;
    int kz = b / ((NN / 64) * NH);
    int rem = b % ((NN / 64) * NH);
    int h  = rem / (NN / 64);
    int n0 = (rem % (NN / 64)) * 64;
    int og4 = (tid & 15) * 4;
    int mg4 = (tid >> 4) * 4;

    float (*xs)[68]  = reinterpret_cast<float(*)[68]>(smem);
    float (*wsh)[68] = reinterpret_cast<float(*)[68]>(smem + 64 * 68);

    float acc[4][4] = {{0.f}};
    const float* xbase0 = x + (size_t)n0 * FIN;
    const float* wbase0 = W + (size_t)h * FIN * HIDN;

    for (int t = 0; t < 2; t++) {
        int k0 = kz * 128 + t * 64;
#pragma unroll
        for (int i = 0; i < 4; i++) {
            int l = tid + i * 256;
            int r = l >> 4;
            int c = (l & 15) * 4;
            *reinterpret_cast<float4*>(&xs[r][c]) =
                *reinterpret_cast<const float4*>(xbase0 + (size_t)r * FIN + k0 + c);
            *reinterpret_cast<float4*>(&wsh[r][c]) =
                *reinterpret_cast<const float4*>(wbase0 + (size_t)(k0 + r) * HIDN + c);
        }
        __syncthreads();

#pragma unroll 8
        for (int k = 0; k < 64; k += 4) {
            float4 xv[4], wv[4];
            xv[0] = *reinterpret_cast<const float4*>(&xs[mg4 + 0][k]);
            xv[1] = *reinterpret_cast<const float4*>(&xs[mg4 + 1][k]);
            xv[2] = *reinterpret_cast<const float4*>(&xs[mg4 + 2][k]);
            xv[3] = *reinterpret_cast<const float4*>(&xs[mg4 + 3][k]);
            wv[0] = *reinterpret_cast<const float4*>(&wsh[k + 0][og4]);
            wv[1] = *reinterpret_cast<const float4*>(&wsh[k + 1][og4]);
            wv[2] = *reinterpret_cast<const float4*>(&wsh[k + 2][og4]);
            wv[3] = *reinterpret_cast<const float4*>(&wsh[k + 3][og4]);
            const float* xf = reinterpret_cast<const float*>(xv);
            const float* wf = reinterpret_cast<const float*>(wv);
#pragma unroll
            for (int i = 0; i < 4; i++) {
#pragma unroll
                for (int kk = 0; kk < 4; kk++) {
                    float xval = xf[i * 4 + kk];
#pragma unroll
                    for (int j = 0; j < 4; j++)
                        acc[i][j] += xval * wf[kk * 4 + j];
                }
            }
        }
        __syncthreads();
    }

    float* outp = Whp + (((size_t)kz * NH + h) * NN + n0 + mg4) * HIDN + og4;
#pragma unroll
    for (int i = 0; i < 4; i++) {
        float4 v = make_float4(acc[i][0], acc[i][1], acc[i][2], acc[i][3]);
        *reinterpret_cast<float4*>(outp + (size_t)i * HIDN) = v;
    }
}

// ---------------- sum K-split partials -> Wh1 (bf16), and compute es/ed (fp32) --------
__global__ __launch_bounds__(256) void k_sum_e1(const float* __restrict__ Whp,
                                                const float* __restrict__ a_src,
                                                const float* __restrict__ a_dst,
                                                ushort* __restrict__ Whb,
                                                float* __restrict__ es,
                                                float* __restrict__ ed) {
    int gw   = blockIdx.x * 4 + (threadIdx.x >> 6);
    int lane = threadIdx.x & 63;
    int h = gw / NN, n = gw % NN;
    size_t idx = ((size_t)h * NN + n) * HIDN + lane;
    size_t stride = (size_t)NH * NN * HIDN;
    float v = Whp[idx] + Whp[idx + stride] + Whp[idx + 2 * stride] + Whp[idx + 3 * stride];
    Whb[idx] = f2bf(v);
    float s = v * a_src[h * HIDN + lane];
    float d = v * a_dst[h * HIDN + lane];
#pragma unroll
    for (int off = 32; off; off >>= 1) {
        s += __shfl_xor(s, off);
        d += __shfl_xor(d, off);
    }
    if (lane == 0) { es[h * NN + n] = s; ed[h * NN + n] = d; }
}

// ---------------- Layer-1 attention + head-mean + ReLU + layer-2 GEMM + e2 --------
// block = 192 (3 waves, wave h = head h); grid = NN
__global__ __launch_bounds__(192) void k_attn1f(const int* __restrict__ nbr,
                                                const int* __restrict__ deg,
                                                const ushort* __restrict__ Whb,
                                                const float* __restrict__ es,
                                                const float* __restrict__ ed,
                                                const float* __restrict__ W2,
                                                const float* __restrict__ a2s,
                                                const float* __restrict__ a2d,
                                                ushort* __restrict__ Wh2b,
                                                float* __restrict__ e2s,
                                                float* __restrict__ e2d) {
    __shared__ unsigned pks[NH][CAP];
    __shared__ float hsum[NH][HIDN];
    int n = blockIdx.x;
    int h = threadIdx.x >> 6;
    int lane = threadIdx.x & 63;
    int d = deg[n];
    const int* nrow = nbr + (size_t)n * CAP;
    float esv = es[h * NN + n];

    float psum = 0.f;
#pragma unroll
    for (int c = 0; c < NCHUNK; c++) {
        int k = c * 64 + lane;
        unsigned u = 0;
        if (k < d) {
            int mm = nrow[k];
            float e = esv + ed[h * NN + mm];
            float s = e > 0.f ? e : LALPHA * e;
            float p = __expf(s);
            u = (__float_as_uint(p) & PK_HIGH) | (unsigned)mm;
            psum += __uint_as_float(u & PK_HIGH);
        }
        pks[h][k] = u;
    }
#pragma unroll
    for (int off = 32; off; off >>= 1) psum += __shfl_xor(psum, off);
    float inv = 1.f / psum;
    __syncthreads();

    // aggregate 4 neighbors / iter: 1 ds_read_b128 + 4 indep bf16 load->FMA chains
    const ushort* WhH = Whb + (size_t)h * NN * HIDN + lane;
    float a0 = 0.f, a1 = 0.f, a2 = 0.f, a3 = 0.f;
    int iters = (d + 3) >> 2;
    for (int g = 0; g < iters; g++) {
        uint4 uu = *reinterpret_cast<const uint4*>(&pks[h][g * 4]);
        a0 += __uint_as_float(uu.x & PK_HIGH) * bf2f(WhH[(size_t)(uu.x & PK_LOW) * HIDN]);
        a1 += __uint_as_float(uu.y & PK_HIGH) * bf2f(WhH[(size_t)(uu.y & PK_LOW) * HIDN]);
        a2 += __uint_as_float(uu.z & PK_HIGH) * bf2f(WhH[(size_t)(uu.z & PK_LOW) * HIDN]);
        a3 += __uint_as_float(uu.w & PK_HIGH) * bf2f(WhH[(size_t)(uu.w & PK_LOW) * HIDN]);
    }
    float hacc = ((a0 + a1) + (a2 + a3));
    hsum[h][lane] = hacc * inv;
    __syncthreads();

    // x2 row value for this lane (identical across waves)
    float xv = (hsum[0][lane] + hsum[1][lane] + hsum[2][lane]) * (1.f / NH);
    xv = fmaxf(xv, 0.f);

    // layer-2 linear for head h: Wh2[h][n][c] = sum_o x2[o] * W2[h][o][c]
    int c = lane < NC ? lane : NC - 1;
    float acc = 0.f;
#pragma unroll 8
    for (int o = 0; o < HIDN; o++) {
        float xb = __shfl(xv, o);
        float wv = W2[((size_t)h * HIDN + o) * NC + c];
        acc += xb * wv;
    }
    if (lane >= NC) acc = 0.f;

    float s2 = acc * (lane < NC ? a2s[h * NC + lane] : 0.f);
    float d2 = acc * (lane < NC ? a2d[h * NC + lane] : 0.f);
#pragma unroll
    for (int off = 32; off; off >>= 1) {
        s2 += __shfl_xor(s2, off);
        d2 += __shfl_xor(d2, off);
    }
    if (lane < NC) Wh2b[((size_t)h * NN + n) * NC + lane] = f2bf(acc);
    if (lane == 0) { e2s[h * NN + n] = s2; e2d[h * NN + n] = d2; }
}

// ---------------- Layer-2 attention + head-mean + log_softmax ----------------
__global__ __launch_bounds__(192) void k_attn2(const int* __restrict__ nbr,
                                               const int* __restrict__ deg,
                                               const ushort* __restrict__ Wh2b,
                                               const float* __restrict__ es,
                                               const float* __restrict__ ed,
                                               float* __restrict__ out) {
    __shared__ unsigned pks[NH][CAP];
    __shared__ float hsum[NH][HIDN];
    int n = blockIdx.x;
    int h = threadIdx.x >> 6;
    int lane = threadIdx.x & 63;
    int d = deg[n];
    const int* nrow = nbr + (size_t)n * CAP;
    float esv = es[h * NN + n];

    float psum = 0.f;
#pragma unroll
    for (int c = 0; c < NCHUNK; c++) {
        int k = c * 64 + lane;
        unsigned u = 0;
        if (k < d) {
            int mm = nrow[k];
            float e = esv + ed[h * NN + mm];
            float s = e > 0.f ? e : LALPHA * e;
            float p = __expf(s);
            u = (__float_as_uint(p) & PK_HIGH) | (unsigned)mm;
            psum += __uint_as_float(u & PK_HIGH);
        }
        pks[h][k] = u;
    }
#pragma unroll
    for (int off = 32; off; off >>= 1) psum += __shfl_xor(psum, off);
    float inv = 1.f / psum;
    __syncthreads();

    const ushort* W2H = Wh2b + (size_t)h * NN * NC + (lane < NC ? lane : 0);
    float a0 = 0.f, a1 = 0.f, a2 = 0.f, a3 = 0.f;
    int iters = (d + 3) >> 2;
    for (int g = 0; g < iters; g++) {
        uint4 uu = *reinterpret_cast<const uint4*>(&pks[h][g * 4]);
        a0 += __uint_as_float(uu.x & PK_HIGH) * bf2f(W2H[(size_t)(uu.x & PK_LOW) * NC]);
        a1 += __uint_as_float(uu.y & PK_HIGH) * bf2f(W2H[(size_t)(uu.y & PK_LOW) * NC]);
        a2 += __uint_as_float(uu.z & PK_HIGH) * bf2f(W2H[(size_t)(uu.z & PK_LOW) * NC]);
        a3 += __uint_as_float(uu.w & PK_HIGH) * bf2f(W2H[(size_t)(uu.w & PK_LOW) * NC]);
    }
    float hacc = ((a0 + a1) + (a2 + a3));
    if (lane < NC) hsum[h][lane] = hacc * inv;
    __syncthreads();

    if (threadIdx.x < 64) {
        float a = (lane < NC)
            ? (hsum[0][lane] + hsum[1][lane] + hsum[2][lane]) * (1.f / NH)
            : -INFINITY;
        float mx = a;
#pragma unroll
        for (int off = 32; off; off >>= 1) mx = fmaxf(mx, __shfl_xor(mx, off));
        float ex = (lane < NC) ? __expf(a - mx) : 0.f;
        float se = ex;
#pragma unroll
        for (int off = 32; off; off >>= 1) se += __shfl_xor(se, off);
        if (lane < NC) out[(size_t)n * NC + lane] = a - mx - logf(se);
    }
}

extern "C" void kernel_launch(void* const* d_in, const int* in_sizes, int n_in,
                              void* d_out, int out_size, void* d_ws, size_t ws_size,
                              hipStream_t stream) {
    const float* feature = (const float*)d_in[0];
    const float* adj     = (const float*)d_in[1];
    const float* W1      = (const float*)d_in[2];
    const float* a1_src  = (const float*)d_in[3];
    const float* a1_dst  = (const float*)d_in[4];
    const float* W2      = (const float*)d_in[5];
    const float* a2_src  = (const float*)d_in[6];
    const float* a2_dst  = (const float*)d_in[7];
    float* out = (float*)d_out;

    char* ws = (char*)d_ws;
    size_t off = 0;
    int*    nbr = (int*)(ws + off);    off += (size_t)NN * CAP * sizeof(int);
    int*    deg = (int*)(ws + off);    off += (size_t)NN * sizeof(int);
    float*  Whp = (float*)(ws + off);  off += (size_t)KSPLIT * NH * NN * HIDN * sizeof(float);
    ushort* Whb = (ushort*)(ws + off); off += (size_t)NH * NN * HIDN * sizeof(ushort);
    float*  e1s = (float*)(ws + off);  off += (size_t)NH * NN * sizeof(float);
    float*  e1d = (float*)(ws + off);  off += (size_t)NH * NN * sizeof(float);
    ushort* Wh2b= (ushort*)(ws + off); off += (size_t)NH * NN * NC * sizeof(ushort);
    float*  e2s = (float*)(ws + off);  off += (size_t)NH * NN * sizeof(float);
    float*  e2d = (float*)(ws + off);  off += (size_t)NH * NN * sizeof(float);

    k_csr_gemm<<<CSRB + GEMMB, 256, 0, stream>>>(adj, nbr, deg, feature, W1, Whp);
    k_sum_e1<<<(NH * NN) / 4, 256, 0, stream>>>(Whp, a1_src, a1_dst, Whb, e1s, e1d);
    k_attn1f<<<NN, 192, 0, stream>>>(nbr, deg, Whb, e1s, e1d, W2, a2_src, a2_dst,
                                     Wh2b, e2s, e2d);
    k_attn2<<<NN, 192, 0, stream>>>(nbr, deg, Wh2b, e2s, e2d, out);
}